// Round 14
// baseline (67.844 us; speedup 1.0000x reference)
//
#include <hip/hip_runtime.h>
#include <hip/hip_fp16.h>
#include <math.h>

#define N_G   1024
#define IMG_H 256
#define IMG_W 256
#define G_EPS 1e-4f
#define LOG2E 1.4426950408889634f
#define CULL_INV_EPS 1.0e5f    // 1/eps, eps = 1e-5 contribution cutoff
#define T_EXIT 1.0e-4f         // early-exit transmittance bound (error <= T_EXIT)
#define N_BLOCKS 512

// ws layout:
//   floats gp[0   ..4095 ] : float4 cullA[1024]  (mx, my, alpha, beta) sorted
//   floats gp[4096..8191 ] : float4 cullB[1024]  (gamma, L, e1, e2)
//   floats gp[8192..16383] : float  rec[1024][8] (mx,my,c2,c3,c4,c5,rg16,b)
//   byte 65536             : uint   counter (memset to 0 per launch)
//
// Single fused kernel, 512 blocks x 512 threads, ALL CO-RESIDENT:
// LDS 47.2KB -> >=2 blocks/CU by LDS, VGPR capped by __launch_bounds__(512,4)
// -> capacity >= 512 blocks, so every block is resident before any completes
// and the producer/consumer flag wait below cannot deadlock.
// Phase A: block b projects+ranks gaussians 2b,2b+1 (parallel prep), then
// release-atomicAdd(counter). Phase B: spin until counter==512 (acquire),
// then per-tile exact cull + compact + composite (identical to R13).
union alignas(16) SMem {
    struct { float sd[N_G]; int red[2][8]; } prep;
    struct { float sgrec[N_G * 8]; float comb[7][4][128]; int wc0[8], wc1[8]; } rend;
};

__global__ __launch_bounds__(512, 4) void fused_kernel(
    const float* __restrict__ means3D,
    const float* __restrict__ covs3d,
    const float* __restrict__ colors,
    const float* __restrict__ opacities,
    const float* __restrict__ Km,
    const float* __restrict__ Rm,
    const float* __restrict__ tv,
    float* __restrict__ gp,
    unsigned* __restrict__ counter,
    float* __restrict__ out)
{
    __shared__ SMem sm;

    const int t  = threadIdx.x;
    const int bi = blockIdx.x;

    // ================= phase A: prep (block b owns gaussians 2b, 2b+1) ======
    {
        const float R20=Rm[6],R21=Rm[7],R22=Rm[8];
        const float t2=tv[2];

        // A1: all 1024 depths (2 per thread)
        #pragma unroll
        for (int k = 0; k < 2; ++k) {
            const int g = t + 512*k;
            const float m0 = means3D[g*3+0], m1 = means3D[g*3+1], m2 = means3D[g*3+2];
            sm.prep.sd[g] = fmaxf(R20*m0 + R21*m1 + R22*m2 + t2, 1.0f);
        }
        __syncthreads();

        // A2: stable rank of gaussian gA = 2*bi + (t>>8); 256 threads each.
        const int h  = t >> 8;          // 0 or 1
        const int tt = t & 255;
        const int gA = 2*bi + h;
        const float di = sm.prep.sd[gA];
        const int j0 = tt * 4;
        const float4 d4 = *(const float4*)&sm.prep.sd[j0];
        int cnt = 0;
        cnt += (d4.x < di) || (d4.x == di && (j0+0) < gA);
        cnt += (d4.y < di) || (d4.y == di && (j0+1) < gA);
        cnt += (d4.z < di) || (d4.z == di && (j0+2) < gA);
        cnt += (d4.w < di) || (d4.w == di && (j0+3) < gA);
        #pragma unroll
        for (int off = 32; off; off >>= 1) cnt += __shfl_down(cnt, off);
        const int wid = t >> 6;         // 0..7
        if ((t & 63) == 0) sm.prep.red[h][wid - 4*h] = cnt;
        __syncthreads();

        // A3: threads 0 and 256 do the full projection for their gaussian
        if ((t & 255) == 0) {
            const int h2 = t >> 8;
            const int gi = 2*bi + h2;
            const int r  = sm.prep.red[h2][0] + sm.prep.red[h2][1]
                         + sm.prep.red[h2][2] + sm.prep.red[h2][3];

            const float m0 = means3D[gi*3+0], m1 = means3D[gi*3+1], m2 = means3D[gi*3+2];
            const float R00=Rm[0],R01=Rm[1],R02=Rm[2];
            const float R10=Rm[3],R11=Rm[4],R12=Rm[5];
            const float t0=tv[0],t1=tv[1];

            const float camx = R00*m0 + R01*m1 + R02*m2 + t0;
            const float camy = R10*m0 + R11*m1 + R12*m2 + t1;
            const float camz = R20*m0 + R21*m1 + R22*m2 + t2;
            const float depth = fmaxf(camz, 1.0f);

            const float K00=Km[0],K01=Km[1],K02=Km[2];
            const float K10=Km[3],K11=Km[4],K12=Km[5];
            const float K20=Km[6],K21=Km[7],K22=Km[8];

            const float u = K00*camx + K01*camy + K02*camz;
            const float v = K10*camx + K11*camy + K12*camz;
            const float z = K20*camx + K21*camy + K22*camz;

            const float mx = u / z;
            const float my = v / z;

            const float inv_z2 = 1.0f / (z*z);
            const float J00 = K00/z - u*inv_z2;
            const float J01 = K01/z - v*inv_z2;
            const float J02 = -u*inv_z2;
            const float J10 = K10/z - u*inv_z2;
            const float J11 = K11/z - v*inv_z2;
            const float J12 = -v*inv_z2;

            const float* S = covs3d + gi*9;
            const float S00=S[0],S01=S[1],S02=S[2];
            const float S10=S[3],S11=S[4],S12=S[5];
            const float S20=S[6],S21=S[7],S22=S[8];

            const float M00 = R00*S00 + R01*S10 + R02*S20;
            const float M01 = R00*S01 + R01*S11 + R02*S21;
            const float M02 = R00*S02 + R01*S12 + R02*S22;
            const float M10 = R10*S00 + R11*S10 + R12*S20;
            const float M11 = R10*S01 + R11*S11 + R12*S21;
            const float M12 = R10*S02 + R11*S12 + R12*S22;
            const float M20 = R20*S00 + R21*S10 + R22*S20;
            const float M21 = R20*S01 + R21*S11 + R22*S21;
            const float M22 = R20*S02 + R21*S12 + R22*S22;

            const float C00 = M00*R00 + M01*R01 + M02*R02;
            const float C01 = M00*R10 + M01*R11 + M02*R12;
            const float C02 = M00*R20 + M01*R21 + M02*R22;
            const float C10 = M10*R00 + M11*R01 + M12*R02;
            const float C11 = M10*R10 + M11*R11 + M12*R12;
            const float C12 = M10*R20 + M11*R21 + M12*R22;
            const float C20 = M20*R00 + M21*R01 + M22*R02;
            const float C21 = M20*R10 + M21*R11 + M22*R12;
            const float C22 = M20*R20 + M21*R21 + M22*R22;

            const float JC00 = J00*C00 + J01*C10 + J02*C20;
            const float JC01 = J00*C01 + J01*C11 + J02*C21;
            const float JC02 = J00*C02 + J01*C12 + J02*C22;
            const float JC10 = J10*C00 + J11*C10 + J12*C20;
            const float JC11 = J10*C01 + J11*C11 + J12*C21;
            const float JC12 = J10*C02 + J11*C12 + J12*C22;

            const float a = JC00*J00 + JC01*J01 + JC02*J02 + G_EPS;
            const float bb= JC00*J10 + JC01*J11 + JC02*J12;
            const float c = JC10*J00 + JC11*J01 + JC12*J02;
            const float d = JC10*J10 + JC11*J11 + JC12*J12 + G_EPS;

            const float det = a*d - bb*c;
            const float inv_det = 1.0f / det;
            const bool valid = (depth > 1.0f) && (depth < 50.0f);
            const float normalizer = 0.15915494309189535f / sqrtf(det);
            const float premult = valid ? (opacities[gi] * normalizer) : 0.0f;

            const float alpha = 0.5f * d * inv_det;
            const float beta  = -0.5f * (bb + c) * inv_det;
            const float gamma = 0.5f * a * inv_det;

            const float ratio = premult * CULL_INV_EPS;
            const float L  = (ratio > 1.0f) ? logf(ratio) : -1.0f;
            const float e1 = -beta / (2.0f * gamma);
            const float e2 = -beta / (2.0f * alpha);

            const float c5 = (premult > 0.0f) ? __log2f(premult) : -1e30f;

            ((float4*)gp)[r]          = make_float4(mx, my, alpha, beta);
            ((float4*)(gp + 4096))[r] = make_float4(gamma, L, e1, e2);

            __half2 rg = __floats2half2_rn(colors[gi*3+0], colors[gi*3+1]);
            const float rgf = __uint_as_float(*reinterpret_cast<unsigned*>(&rg));

            float* o = gp + 8192 + r*8;
            *(float4*)(o + 0) = make_float4(mx, my, -alpha * LOG2E, -beta * LOG2E);
            *(float4*)(o + 4) = make_float4(-gamma * LOG2E, c5, rgf, colors[gi*3+2]);

            __threadfence();    // writer-side: push records to device scope
        }
        __syncthreads();

        // signal + wait (all 512 blocks co-resident: cannot deadlock)
        if (t == 0) {
            __hip_atomic_fetch_add(counter, 1u, __ATOMIC_RELEASE,
                                   __HIP_MEMORY_SCOPE_AGENT);
            while (__hip_atomic_load(counter, __ATOMIC_ACQUIRE,
                                     __HIP_MEMORY_SCOPE_AGENT) < N_BLOCKS)
                __builtin_amdgcn_s_sleep(2);
        }
        __syncthreads();
    }

    // ================= phase B: render (R13 structure) ======================
    const int lane = t & 63;
    const int w    = t >> 6;

    const int i  = bi & 255;
    const int qq = bi >> 8;         // 0 or 1
    const int x0 = i & 15;
    const int y0 = i >> 4;          // 0..15
    const int tx = qq ? ((x0 + 8) & 15) : x0;
    const int ty = qq ? (y0 + 16) : y0;

    const float cx = (float)(tx << 4) + 7.5f;
    const float cy = (float)(ty << 3) + 3.5f;

    const float4* cullA = (const float4*)gp;
    const float4* cullB = (const float4*)(gp + 4096);
    const float*  rec   = gp + 8192;

    auto keep_test = [&](int g) -> bool {
        const float4 A = cullA[g];   // mx,my,alpha,beta
        const float4 B = cullB[g];   // gamma,L,e1,e2
        const float bx0 = cx - 7.5f - A.x, bx1 = bx0 + 15.0f;
        const float by0 = cy - 3.5f - A.y, by1 = by0 + 7.0f;
        float dy = fminf(fmaxf(B.z * bx0, by0), by1);
        float qm = fmaf(B.x * dy, dy, bx0 * fmaf(A.w, dy, A.z * bx0));
        dy = fminf(fmaxf(B.z * bx1, by0), by1);
        qm = fminf(qm, fmaf(B.x * dy, dy, bx1 * fmaf(A.w, dy, A.z * bx1)));
        float dxq = fminf(fmaxf(B.w * by0, bx0), bx1);
        qm = fminf(qm, fmaf(A.z * dxq, dxq, by0 * fmaf(A.w, dxq, B.x * by0)));
        dxq = fminf(fmaxf(B.w * by1, bx0), bx1);
        qm = fminf(qm, fmaf(A.z * dxq, dxq, by1 * fmaf(A.w, dxq, B.x * by1)));
        if ((bx0 <= 0.0f) & (bx1 >= 0.0f) & (by0 <= 0.0f) & (by1 >= 0.0f))
            qm = 0.0f;
        return qm <= B.y;
    };

    // --- cull + order-preserving compaction + stage records to LDS ---
    const int ga = t, gb = 512 + t;
    const bool keepA = keep_test(ga);
    const bool keepB = keep_test(gb);
    const unsigned long long bmA = __ballot(keepA);
    const unsigned long long bmB = __ballot(keepB);
    if (lane == 0) { sm.rend.wc0[w] = __popcll(bmA); sm.rend.wc1[w] = __popcll(bmB); }
    __syncthreads();
    int baseA = 0, baseB = 0, sumA = 0, total = 0;
    #pragma unroll
    for (int ii = 0; ii < 8; ++ii) {
        const int c0 = sm.rend.wc0[ii], c1 = sm.rend.wc1[ii];
        if (ii < w) { baseA += c0; baseB += c1; }
        sumA  += c0;
        total += c0 + c1;
    }
    if (keepA) {
        const int pos = baseA + __popcll(bmA & ((1ull << lane) - 1ull));
        const float4* s4 = (const float4*)(rec + ga*8);
        float4* dst = (float4*)&sm.rend.sgrec[pos * 8];
        dst[0] = s4[0]; dst[1] = s4[1];
    }
    if (keepB) {
        const int pos = sumA + baseB + __popcll(bmB & ((1ull << lane) - 1ull));
        const float4* s4 = (const float4*)(rec + gb*8);
        float4* dst = (float4*)&sm.rend.sgrec[pos * 8];
        dst[0] = s4[0]; dst[1] = s4[1];
    }
    __syncthreads();

    // --- composite: 2 pixels per lane, segments over depth ---
    const int lx = lane & 15;
    const int ly = lane >> 4;       // 0..3
    const int s  = w;               // segment 0..7
    const int px  = (tx << 4) + lx;
    const int py0 = (ty << 3) + ly; // second pixel at py0+4
    const float fpx = (float)px, fpy0 = (float)py0;

    const int seg = (total + 7) >> 3;
    const int k0 = s * seg;
    const int k1 = (k0 + seg < total) ? (k0 + seg) : total;

    float T0 = 1.0f, cr0 = 0.0f, cg0 = 0.0f, cb0 = 0.0f;
    float T1 = 1.0f, cr1 = 0.0f, cg1 = 0.0f, cb1 = 0.0f;

    int iter = 0;
    for (int k = k0; k < k1; ++k) {
        const float4* g4 = (const float4*)&sm.rend.sgrec[k * 8];
        const float4 A = g4[0];  // mx,my,c2,c3
        const float4 B = g4[1];  // c4,c5,rg16,b

        const float dx   = fpx - A.x;
        const float c2dx = A.z * dx;
        const float dy0  = fpy0 - A.y;
        const float dy1  = dy0 + 4.0f;

        const float t10 = fmaf(A.w, dy0, c2dx);
        const float t11 = fmaf(A.w, dy1, c2dx);
        const float h0  = fmaf(B.x * dy0, dy0, B.y);
        const float h1  = fmaf(B.x * dy1, dy1, B.y);
        const float P0  = fmaf(dx, t10, h0);
        const float P1  = fmaf(dx, t11, h1);
        const float al0 = __builtin_amdgcn_exp2f(P0);
        const float al1 = __builtin_amdgcn_exp2f(P1);

        unsigned rgbits = __float_as_uint(B.z);
        const float2 rg = __half22float2(*reinterpret_cast<__half2*>(&rgbits));

        const float w0 = T0 * al0;
        const float w1 = T1 * al1;
        cr0 = fmaf(w0, rg.x, cr0);  cr1 = fmaf(w1, rg.x, cr1);
        cg0 = fmaf(w0, rg.y, cg0);  cg1 = fmaf(w1, rg.y, cg1);
        cb0 = fmaf(w0, B.w, cb0);   cb1 = fmaf(w1, B.w, cb1);
        T0  = fmaf(-al0, T0, T0);   T1  = fmaf(-al1, T1, T1);

        if (((++iter) & 1) == 0 && __all(fmaxf(T0, T1) < T_EXIT)) break;
    }

    if (s > 0) {
        sm.rend.comb[s-1][0][lane]    = T0;
        sm.rend.comb[s-1][1][lane]    = cr0;
        sm.rend.comb[s-1][2][lane]    = cg0;
        sm.rend.comb[s-1][3][lane]    = cb0;
        sm.rend.comb[s-1][0][lane+64] = T1;
        sm.rend.comb[s-1][1][lane+64] = cr1;
        sm.rend.comb[s-1][2][lane+64] = cg1;
        sm.rend.comb[s-1][3][lane+64] = cb1;
    }
    __syncthreads();

    if (s == 0) {
        #pragma unroll
        for (int si = 0; si < 7; ++si) {
            cr0 = fmaf(T0, sm.rend.comb[si][1][lane], cr0);
            cg0 = fmaf(T0, sm.rend.comb[si][2][lane], cg0);
            cb0 = fmaf(T0, sm.rend.comb[si][3][lane], cb0);
            T0 *= sm.rend.comb[si][0][lane];
            cr1 = fmaf(T1, sm.rend.comb[si][1][lane+64], cr1);
            cg1 = fmaf(T1, sm.rend.comb[si][2][lane+64], cg1);
            cb1 = fmaf(T1, sm.rend.comb[si][3][lane+64], cb1);
            T1 *= sm.rend.comb[si][0][lane+64];
        }
        const int pid0 = py0 * IMG_W + px;
        const int pid1 = (py0 + 4) * IMG_W + px;
        out[pid0*3 + 0] = cr0;
        out[pid0*3 + 1] = cg0;
        out[pid0*3 + 2] = cb0;
        out[pid1*3 + 0] = cr1;
        out[pid1*3 + 1] = cg1;
        out[pid1*3 + 2] = cb1;
    }
}

extern "C" void kernel_launch(void* const* d_in, const int* in_sizes, int n_in,
                              void* d_out, int out_size, void* d_ws, size_t ws_size,
                              hipStream_t stream) {
    const float* means3D   = (const float*)d_in[0];
    const float* covs3d    = (const float*)d_in[1];
    const float* colors    = (const float*)d_in[2];
    const float* opacities = (const float*)d_in[3];
    const float* Km        = (const float*)d_in[4];
    const float* Rm        = (const float*)d_in[5];
    const float* tv        = (const float*)d_in[6];

    float*    gp      = (float*)d_ws;                      // 64 KB records
    unsigned* counter = (unsigned*)((char*)d_ws + 65536);  // 4 B flag

    hipMemsetAsync(counter, 0, 4, stream);
    hipLaunchKernelGGL(fused_kernel, dim3(512), dim3(512), 0, stream,
                       means3D, covs3d, colors, opacities, Km, Rm, tv,
                       gp, counter, (float*)d_out);
}

// Round 15
// 15.934 us; speedup vs baseline: 4.2579x; 4.2579x over previous
//
#include <hip/hip_runtime.h>
#include <hip/hip_fp16.h>
#include <math.h>

#define N_G   1024
#define IMG_H 256
#define IMG_W 256
#define G_EPS 1e-4f
#define LOG2E 1.4426950408889634f
#define CULL_INV_EPS 3.3333e4f // 1/eps, eps = 3e-5 contribution cutoff
#define T_EXIT 3.0e-4f         // early-exit transmittance bound (error <= T_EXIT)

// ws layout (floats):
//   gp[0   ..4095 ] : float4 cullA[1024]  (mx, my, alpha, beta)   sorted order
//   gp[4096..8191 ] : float4 cullB[1024]  (gamma, L, e1, e2)
//   gp[8192..16383] : float  rec[1024][8] (mx,my,c2,c3,c4,c5,rg16,b)
//
// Prep: 64 blocks x 256 threads; block b owns gaussians [16b, 16b+16).
// Rank scan split 16-way per gaussian; chunk-interleaved float4 broadcast
// reads keep the 4 q-groups of a wave on disjoint banks.
// ---------------------------------------------------------------------------
__global__ __launch_bounds__(256) void prep_sort_kernel(
    const float* __restrict__ means3D,
    const float* __restrict__ covs3d,
    const float* __restrict__ colors,
    const float* __restrict__ opacities,
    const float* __restrict__ Km,
    const float* __restrict__ Rm,
    const float* __restrict__ tv,
    float* __restrict__ gp)
{
    __shared__ alignas(16) float sd[N_G];
    __shared__ int pr[16][17];

    const int t = threadIdx.x;
    const int b = blockIdx.x;       // 0..63

    const float R20=Rm[6],R21=Rm[7],R22=Rm[8];
    const float t2=tv[2];

    // phase 1: all 1024 depths, 4 per thread
    #pragma unroll
    for (int k = 0; k < 4; ++k) {
        const int g = t + 256*k;
        const float m0 = means3D[g*3+0], m1 = means3D[g*3+1], m2 = means3D[g*3+2];
        sd[g] = fmaxf(R20*m0 + R21*m1 + R22*m2 + t2, 1.0f);
    }
    __syncthreads();

    // phase 2: partial stable rank. thread = (li = t&15, q = t>>4).
    const int li = t & 15;
    const int q  = t >> 4;          // 0..15
    const int i  = b*16 + li;
    const float di = sd[i];
    int rank = 0;
    #pragma unroll
    for (int jj = 0; jj < 16; ++jj) {
        const int c = q + 16*jj;    // chunk of 4 elements
        const int j = c * 4;
        const float4 d4 = *(const float4*)&sd[j];
        rank += (d4.x < di) || (d4.x == di && (j+0) < i);
        rank += (d4.y < di) || (d4.y == di && (j+1) < i);
        rank += (d4.z < di) || (d4.z == di && (j+2) < i);
        rank += (d4.w < di) || (d4.w == di && (j+3) < i);
    }
    pr[li][q] = rank;
    __syncthreads();

    // phase 3: first 16 threads: full projection + records at sorted position
    if (t < 16) {
        const int gi = b*16 + t;
        int r = 0;
        #pragma unroll
        for (int q2 = 0; q2 < 16; ++q2) r += pr[t][q2];

        const float m0 = means3D[gi*3+0], m1 = means3D[gi*3+1], m2 = means3D[gi*3+2];
        const float R00=Rm[0],R01=Rm[1],R02=Rm[2];
        const float R10=Rm[3],R11=Rm[4],R12=Rm[5];
        const float t0=tv[0],t1=tv[1];

        const float camx = R00*m0 + R01*m1 + R02*m2 + t0;
        const float camy = R10*m0 + R11*m1 + R12*m2 + t1;
        const float camz = R20*m0 + R21*m1 + R22*m2 + t2;
        const float depth = fmaxf(camz, 1.0f);

        const float K00=Km[0],K01=Km[1],K02=Km[2];
        const float K10=Km[3],K11=Km[4],K12=Km[5];
        const float K20=Km[6],K21=Km[7],K22=Km[8];

        const float u = K00*camx + K01*camy + K02*camz;
        const float v = K10*camx + K11*camy + K12*camz;
        const float z = K20*camx + K21*camy + K22*camz;

        const float mx = u / z;
        const float my = v / z;

        const float inv_z2 = 1.0f / (z*z);
        const float J00 = K00/z - u*inv_z2;
        const float J01 = K01/z - v*inv_z2;
        const float J02 = -u*inv_z2;
        const float J10 = K10/z - u*inv_z2;
        const float J11 = K11/z - v*inv_z2;
        const float J12 = -v*inv_z2;

        const float* S = covs3d + gi*9;
        const float S00=S[0],S01=S[1],S02=S[2];
        const float S10=S[3],S11=S[4],S12=S[5];
        const float S20=S[6],S21=S[7],S22=S[8];

        // M = R*S
        const float M00 = R00*S00 + R01*S10 + R02*S20;
        const float M01 = R00*S01 + R01*S11 + R02*S21;
        const float M02 = R00*S02 + R01*S12 + R02*S22;
        const float M10 = R10*S00 + R11*S10 + R12*S20;
        const float M11 = R10*S01 + R11*S11 + R12*S21;
        const float M12 = R10*S02 + R11*S12 + R12*S22;
        const float M20 = R20*S00 + R21*S10 + R22*S20;
        const float M21 = R20*S01 + R21*S11 + R22*S21;
        const float M22 = R20*S02 + R21*S12 + R22*S22;

        // C = M*R^T
        const float C00 = M00*R00 + M01*R01 + M02*R02;
        const float C01 = M00*R10 + M01*R11 + M02*R12;
        const float C02 = M00*R20 + M01*R21 + M02*R22;
        const float C10 = M10*R00 + M11*R01 + M12*R02;
        const float C11 = M10*R10 + M11*R11 + M12*R12;
        const float C12 = M10*R20 + M11*R21 + M12*R22;
        const float C20 = M20*R00 + M21*R01 + M22*R02;
        const float C21 = M20*R10 + M21*R11 + M22*R12;
        const float C22 = M20*R20 + M21*R21 + M22*R22;

        // JC = J*C (2x3)
        const float JC00 = J00*C00 + J01*C10 + J02*C20;
        const float JC01 = J00*C01 + J01*C11 + J02*C21;
        const float JC02 = J00*C02 + J01*C12 + J02*C22;
        const float JC10 = J10*C00 + J11*C10 + J12*C20;
        const float JC11 = J10*C01 + J11*C11 + J12*C21;
        const float JC12 = J10*C02 + J11*C12 + J12*C22;

        // V = JC*J^T + EPS*I
        const float a = JC00*J00 + JC01*J01 + JC02*J02 + G_EPS;
        const float bb= JC00*J10 + JC01*J11 + JC02*J12;
        const float c = JC10*J00 + JC11*J01 + JC12*J02;
        const float d = JC10*J10 + JC11*J11 + JC12*J12 + G_EPS;

        const float det = a*d - bb*c;
        const float inv_det = 1.0f / det;
        const bool valid = (depth > 1.0f) && (depth < 50.0f);
        const float normalizer = 0.15915494309189535f / sqrtf(det);
        const float premult = valid ? (opacities[gi] * normalizer) : 0.0f;

        // ln-domain conic: q(d) = alpha*dx^2 + beta*dx*dy + gamma*dy^2
        const float alpha = 0.5f * d * inv_det;
        const float beta  = -0.5f * (bb + c) * inv_det;
        const float gamma = 0.5f * a * inv_det;

        const float ratio = premult * CULL_INV_EPS;   // premult/eps
        const float L  = (ratio > 1.0f) ? logf(ratio) : -1.0f;
        const float e1 = -beta / (2.0f * gamma);
        const float e2 = -beta / (2.0f * alpha);

        const float c5 = (premult > 0.0f) ? __log2f(premult) : -1e30f;

        ((float4*)gp)[r]          = make_float4(mx, my, alpha, beta);
        ((float4*)(gp + 4096))[r] = make_float4(gamma, L, e1, e2);

        __half2 rg = __floats2half2_rn(colors[gi*3+0], colors[gi*3+1]);
        const float rgf = __uint_as_float(*reinterpret_cast<unsigned*>(&rg));

        float* o = gp + 8192 + r*8;
        *(float4*)(o + 0) = make_float4(mx, my,
                                        -alpha * LOG2E,
                                        -beta  * LOG2E);
        *(float4*)(o + 4) = make_float4(-gamma * LOG2E,
                                        c5,
                                        rgf,
                                        colors[gi*3+2]);
    }
}

// ---------------------------------------------------------------------------
// Kernel 2: per-tile EXACT cull + compact + composite, 2 pixels per lane.
// Grid 512 blocks x 512 threads; block = one 16x8 tile via load-balance
// permutation. 46.3 KB LDS (best measured config).
// Early exit: own-segment T >= global T, so breaking when all lanes have
// T < T_EXIT under-counts by at most T_EXIT per pixel; checked every 2 visits.
// ---------------------------------------------------------------------------
__global__ __launch_bounds__(512, 4) void render_kernel(
    const float* __restrict__ gp, float* __restrict__ out)
{
    __shared__ alignas(16) float sgrec[N_G * 8];   // 32 KB
    __shared__ float comb[7][4][128];              // 14 KB
    __shared__ int wc0[8], wc1[8];

    const int t    = threadIdx.x;
    const int lane = t & 63;
    const int w    = t >> 6;

    // block -> tile permutation: 512 tiles (16 x-tiles, 32 y-tiles).
    const int bi = blockIdx.x;
    const int i  = bi & 255;
    const int qq = bi >> 8;         // 0 or 1
    const int x0 = i & 15;
    const int y0 = i >> 4;          // 0..15
    const int tx = qq ? ((x0 + 8) & 15) : x0;
    const int ty = qq ? (y0 + 16) : y0;

    const float cx = (float)(tx << 4) + 7.5f;
    const float cy = (float)(ty << 3) + 3.5f;

    const float4* cullA = (const float4*)gp;
    const float4* cullB = (const float4*)(gp + 4096);
    const float*  rec   = gp + 8192;

    // exact ellipse-vs-rect test (rect = pixel centers of tile)
    auto keep_test = [&](int g) -> bool {
        const float4 A = cullA[g];   // mx,my,alpha,beta
        const float4 B = cullB[g];   // gamma,L,e1,e2
        const float bx0 = cx - 7.5f - A.x, bx1 = bx0 + 15.0f;
        const float by0 = cy - 3.5f - A.y, by1 = by0 + 7.0f;
        float dy = fminf(fmaxf(B.z * bx0, by0), by1);
        float qm = fmaf(B.x * dy, dy, bx0 * fmaf(A.w, dy, A.z * bx0));
        dy = fminf(fmaxf(B.z * bx1, by0), by1);
        qm = fminf(qm, fmaf(B.x * dy, dy, bx1 * fmaf(A.w, dy, A.z * bx1)));
        float dxq = fminf(fmaxf(B.w * by0, bx0), bx1);
        qm = fminf(qm, fmaf(A.z * dxq, dxq, by0 * fmaf(A.w, dxq, B.x * by0)));
        dxq = fminf(fmaxf(B.w * by1, bx0), bx1);
        qm = fminf(qm, fmaf(A.z * dxq, dxq, by1 * fmaf(A.w, dxq, B.x * by1)));
        if ((bx0 <= 0.0f) & (bx1 >= 0.0f) & (by0 <= 0.0f) & (by1 >= 0.0f))
            qm = 0.0f;
        return qm <= B.y;
    };

    // --- cull + order-preserving compaction + stage records to LDS ---
    const int ga = t, gb = 512 + t;
    const bool keepA = keep_test(ga);
    const bool keepB = keep_test(gb);
    const unsigned long long bmA = __ballot(keepA);
    const unsigned long long bmB = __ballot(keepB);
    if (lane == 0) { wc0[w] = __popcll(bmA); wc1[w] = __popcll(bmB); }
    __syncthreads();
    int baseA = 0, baseB = 0, sumA = 0, total = 0;
    #pragma unroll
    for (int ii = 0; ii < 8; ++ii) {
        const int c0 = wc0[ii], c1 = wc1[ii];
        if (ii < w) { baseA += c0; baseB += c1; }
        sumA  += c0;
        total += c0 + c1;
    }
    if (keepA) {
        const int pos = baseA + __popcll(bmA & ((1ull << lane) - 1ull));
        const float4* s4 = (const float4*)(rec + ga*8);
        float4* dst = (float4*)&sgrec[pos * 8];
        dst[0] = s4[0]; dst[1] = s4[1];
    }
    if (keepB) {
        const int pos = sumA + baseB + __popcll(bmB & ((1ull << lane) - 1ull));
        const float4* s4 = (const float4*)(rec + gb*8);
        float4* dst = (float4*)&sgrec[pos * 8];
        dst[0] = s4[0]; dst[1] = s4[1];
    }
    __syncthreads();

    // --- composite: 2 pixels per lane, segments over depth ---
    const int lx = lane & 15;
    const int ly = lane >> 4;       // 0..3
    const int s  = w;               // segment 0..7
    const int px  = (tx << 4) + lx;
    const int py0 = (ty << 3) + ly; // second pixel at py0+4
    const float fpx = (float)px, fpy0 = (float)py0;

    const int seg = (total + 7) >> 3;
    const int k0 = s * seg;
    const int k1 = (k0 + seg < total) ? (k0 + seg) : total;

    float T0 = 1.0f, cr0 = 0.0f, cg0 = 0.0f, cb0 = 0.0f;
    float T1 = 1.0f, cr1 = 0.0f, cg1 = 0.0f, cb1 = 0.0f;

    int iter = 0;
    for (int k = k0; k < k1; ++k) {
        const float4* g4 = (const float4*)&sgrec[k * 8];
        const float4 A = g4[0];  // mx,my,c2,c3
        const float4 B = g4[1];  // c4,c5,rg16,b

        const float dx   = fpx - A.x;           // shared between both pixels
        const float c2dx = A.z * dx;
        const float dy0  = fpy0 - A.y;
        const float dy1  = dy0 + 4.0f;

        const float t10 = fmaf(A.w, dy0, c2dx);
        const float t11 = fmaf(A.w, dy1, c2dx);
        const float h0  = fmaf(B.x * dy0, dy0, B.y);
        const float h1  = fmaf(B.x * dy1, dy1, B.y);
        const float P0  = fmaf(dx, t10, h0);
        const float P1  = fmaf(dx, t11, h1);
        const float al0 = __builtin_amdgcn_exp2f(P0);
        const float al1 = __builtin_amdgcn_exp2f(P1);

        unsigned rgbits = __float_as_uint(B.z);
        const float2 rg = __half22float2(*reinterpret_cast<__half2*>(&rgbits));

        const float w0 = T0 * al0;
        const float w1 = T1 * al1;
        cr0 = fmaf(w0, rg.x, cr0);  cr1 = fmaf(w1, rg.x, cr1);
        cg0 = fmaf(w0, rg.y, cg0);  cg1 = fmaf(w1, rg.y, cg1);
        cb0 = fmaf(w0, B.w, cb0);   cb1 = fmaf(w1, B.w, cb1);
        T0  = fmaf(-al0, T0, T0);   T1  = fmaf(-al1, T1, T1);

        // conservative early exit (own-T >= global-T), every 2 visits
        if (((++iter) & 1) == 0 && __all(fmaxf(T0, T1) < T_EXIT)) break;
    }

    if (s > 0) {
        comb[s-1][0][lane]    = T0;
        comb[s-1][1][lane]    = cr0;
        comb[s-1][2][lane]    = cg0;
        comb[s-1][3][lane]    = cb0;
        comb[s-1][0][lane+64] = T1;
        comb[s-1][1][lane+64] = cr1;
        comb[s-1][2][lane+64] = cg1;
        comb[s-1][3][lane+64] = cb1;
    }
    __syncthreads();

    if (s == 0) {
        #pragma unroll
        for (int si = 0; si < 7; ++si) {
            cr0 = fmaf(T0, comb[si][1][lane], cr0);
            cg0 = fmaf(T0, comb[si][2][lane], cg0);
            cb0 = fmaf(T0, comb[si][3][lane], cb0);
            T0 *= comb[si][0][lane];
            cr1 = fmaf(T1, comb[si][1][lane+64], cr1);
            cg1 = fmaf(T1, comb[si][2][lane+64], cg1);
            cb1 = fmaf(T1, comb[si][3][lane+64], cb1);
            T1 *= comb[si][0][lane+64];
        }
        const int pid0 = py0 * IMG_W + px;
        const int pid1 = (py0 + 4) * IMG_W + px;
        out[pid0*3 + 0] = cr0;
        out[pid0*3 + 1] = cg0;
        out[pid0*3 + 2] = cb0;
        out[pid1*3 + 0] = cr1;
        out[pid1*3 + 1] = cg1;
        out[pid1*3 + 2] = cb1;
    }
}

extern "C" void kernel_launch(void* const* d_in, const int* in_sizes, int n_in,
                              void* d_out, int out_size, void* d_ws, size_t ws_size,
                              hipStream_t stream) {
    const float* means3D   = (const float*)d_in[0];
    const float* covs3d    = (const float*)d_in[1];
    const float* colors    = (const float*)d_in[2];
    const float* opacities = (const float*)d_in[3];
    const float* Km        = (const float*)d_in[4];
    const float* Rm        = (const float*)d_in[5];
    const float* tv        = (const float*)d_in[6];

    float* gp = (float*)d_ws;   // 64 KB used

    hipLaunchKernelGGL(prep_sort_kernel, dim3(64), dim3(256), 0, stream,
                       means3D, covs3d, colors, opacities, Km, Rm, tv, gp);
    hipLaunchKernelGGL(render_kernel, dim3(512), dim3(512), 0, stream,
                       gp, (float*)d_out);
}

// Round 16
// 15.409 us; speedup vs baseline: 4.4029x; 1.0340x over previous
//
#include <hip/hip_runtime.h>
#include <hip/hip_fp16.h>
#include <math.h>

#define N_G   1024
#define IMG_H 256
#define IMG_W 256
#define G_EPS 1e-4f
#define LOG2E 1.4426950408889634f
#define CULL_INV_EPS 1.0e4f    // 1/eps, eps = 1e-4 contribution cutoff
#define T_EXIT 3.0e-4f         // early-exit transmittance bound (error <= T_EXIT)

// ws layout (floats):
//   gp[0   ..4095 ] : float4 cullA[1024]  (mx, my, alpha, beta)   sorted order
//   gp[4096..8191 ] : float4 cullB[1024]  (gamma, L, e1, e2)
//   gp[8192..16383] : float  rec[1024][8] (mx,my,c2,c3,c4,c5,rg16,b)
//
// Prep: 64 blocks x 256 threads; block b owns gaussians [16b, 16b+16).
// Rank scan split 16-way per gaussian; chunk-interleaved float4 broadcast
// reads keep the 4 q-groups of a wave on disjoint banks.
// ---------------------------------------------------------------------------
__global__ __launch_bounds__(256) void prep_sort_kernel(
    const float* __restrict__ means3D,
    const float* __restrict__ covs3d,
    const float* __restrict__ colors,
    const float* __restrict__ opacities,
    const float* __restrict__ Km,
    const float* __restrict__ Rm,
    const float* __restrict__ tv,
    float* __restrict__ gp)
{
    __shared__ alignas(16) float sd[N_G];
    __shared__ int pr[16][17];

    const int t = threadIdx.x;
    const int b = blockIdx.x;       // 0..63

    const float R20=Rm[6],R21=Rm[7],R22=Rm[8];
    const float t2=tv[2];

    // phase 1: all 1024 depths, 4 per thread
    #pragma unroll
    for (int k = 0; k < 4; ++k) {
        const int g = t + 256*k;
        const float m0 = means3D[g*3+0], m1 = means3D[g*3+1], m2 = means3D[g*3+2];
        sd[g] = fmaxf(R20*m0 + R21*m1 + R22*m2 + t2, 1.0f);
    }
    __syncthreads();

    // phase 2: partial stable rank. thread = (li = t&15, q = t>>4).
    const int li = t & 15;
    const int q  = t >> 4;          // 0..15
    const int i  = b*16 + li;
    const float di = sd[i];
    int rank = 0;
    #pragma unroll
    for (int jj = 0; jj < 16; ++jj) {
        const int c = q + 16*jj;    // chunk of 4 elements
        const int j = c * 4;
        const float4 d4 = *(const float4*)&sd[j];
        rank += (d4.x < di) || (d4.x == di && (j+0) < i);
        rank += (d4.y < di) || (d4.y == di && (j+1) < i);
        rank += (d4.z < di) || (d4.z == di && (j+2) < i);
        rank += (d4.w < di) || (d4.w == di && (j+3) < i);
    }
    pr[li][q] = rank;
    __syncthreads();

    // phase 3: first 16 threads: full projection + records at sorted position
    if (t < 16) {
        const int gi = b*16 + t;
        int r = 0;
        #pragma unroll
        for (int q2 = 0; q2 < 16; ++q2) r += pr[t][q2];

        const float m0 = means3D[gi*3+0], m1 = means3D[gi*3+1], m2 = means3D[gi*3+2];
        const float R00=Rm[0],R01=Rm[1],R02=Rm[2];
        const float R10=Rm[3],R11=Rm[4],R12=Rm[5];
        const float t0=tv[0],t1=tv[1];

        const float camx = R00*m0 + R01*m1 + R02*m2 + t0;
        const float camy = R10*m0 + R11*m1 + R12*m2 + t1;
        const float camz = R20*m0 + R21*m1 + R22*m2 + t2;
        const float depth = fmaxf(camz, 1.0f);

        const float K00=Km[0],K01=Km[1],K02=Km[2];
        const float K10=Km[3],K11=Km[4],K12=Km[5];
        const float K20=Km[6],K21=Km[7],K22=Km[8];

        const float u = K00*camx + K01*camy + K02*camz;
        const float v = K10*camx + K11*camy + K12*camz;
        const float z = K20*camx + K21*camy + K22*camz;

        const float mx = u / z;
        const float my = v / z;

        const float inv_z2 = 1.0f / (z*z);
        const float J00 = K00/z - u*inv_z2;
        const float J01 = K01/z - v*inv_z2;
        const float J02 = -u*inv_z2;
        const float J10 = K10/z - u*inv_z2;
        const float J11 = K11/z - v*inv_z2;
        const float J12 = -v*inv_z2;

        const float* S = covs3d + gi*9;
        const float S00=S[0],S01=S[1],S02=S[2];
        const float S10=S[3],S11=S[4],S12=S[5];
        const float S20=S[6],S21=S[7],S22=S[8];

        // M = R*S
        const float M00 = R00*S00 + R01*S10 + R02*S20;
        const float M01 = R00*S01 + R01*S11 + R02*S21;
        const float M02 = R00*S02 + R01*S12 + R02*S22;
        const float M10 = R10*S00 + R11*S10 + R12*S20;
        const float M11 = R10*S01 + R11*S11 + R12*S21;
        const float M12 = R10*S02 + R11*S12 + R12*S22;
        const float M20 = R20*S00 + R21*S10 + R22*S20;
        const float M21 = R20*S01 + R21*S11 + R22*S21;
        const float M22 = R20*S02 + R21*S12 + R22*S22;

        // C = M*R^T
        const float C00 = M00*R00 + M01*R01 + M02*R02;
        const float C01 = M00*R10 + M01*R11 + M02*R12;
        const float C02 = M00*R20 + M01*R21 + M02*R22;
        const float C10 = M10*R00 + M11*R01 + M12*R02;
        const float C11 = M10*R10 + M11*R11 + M12*R12;
        const float C12 = M10*R20 + M11*R21 + M12*R22;
        const float C20 = M20*R00 + M21*R01 + M22*R02;
        const float C21 = M20*R10 + M21*R11 + M22*R12;
        const float C22 = M20*R20 + M21*R21 + M22*R22;

        // JC = J*C (2x3)
        const float JC00 = J00*C00 + J01*C10 + J02*C20;
        const float JC01 = J00*C01 + J01*C11 + J02*C21;
        const float JC02 = J00*C02 + J01*C12 + J02*C22;
        const float JC10 = J10*C00 + J11*C10 + J12*C20;
        const float JC11 = J10*C01 + J11*C11 + J12*C21;
        const float JC12 = J10*C02 + J11*C12 + J12*C22;

        // V = JC*J^T + EPS*I
        const float a = JC00*J00 + JC01*J01 + JC02*J02 + G_EPS;
        const float bb= JC00*J10 + JC01*J11 + JC02*J12;
        const float c = JC10*J00 + JC11*J01 + JC12*J02;
        const float d = JC10*J10 + JC11*J11 + JC12*J12 + G_EPS;

        const float det = a*d - bb*c;
        const float inv_det = 1.0f / det;
        const bool valid = (depth > 1.0f) && (depth < 50.0f);
        const float normalizer = 0.15915494309189535f / sqrtf(det);
        const float premult = valid ? (opacities[gi] * normalizer) : 0.0f;

        // ln-domain conic: q(d) = alpha*dx^2 + beta*dx*dy + gamma*dy^2
        const float alpha = 0.5f * d * inv_det;
        const float beta  = -0.5f * (bb + c) * inv_det;
        const float gamma = 0.5f * a * inv_det;

        const float ratio = premult * CULL_INV_EPS;   // premult/eps
        const float L  = (ratio > 1.0f) ? logf(ratio) : -1.0f;
        const float e1 = -beta / (2.0f * gamma);
        const float e2 = -beta / (2.0f * alpha);

        const float c5 = (premult > 0.0f) ? __log2f(premult) : -1e30f;

        ((float4*)gp)[r]          = make_float4(mx, my, alpha, beta);
        ((float4*)(gp + 4096))[r] = make_float4(gamma, L, e1, e2);

        __half2 rg = __floats2half2_rn(colors[gi*3+0], colors[gi*3+1]);
        const float rgf = __uint_as_float(*reinterpret_cast<unsigned*>(&rg));

        float* o = gp + 8192 + r*8;
        *(float4*)(o + 0) = make_float4(mx, my,
                                        -alpha * LOG2E,
                                        -beta  * LOG2E);
        *(float4*)(o + 4) = make_float4(-gamma * LOG2E,
                                        c5,
                                        rgf,
                                        colors[gi*3+2]);
    }
}

// ---------------------------------------------------------------------------
// Kernel 2: per-tile EXACT cull + compact + composite, 2 pixels per lane.
// Grid 512 blocks x 512 threads; block = one 16x8 tile via load-balance
// permutation. 46.3 KB LDS (best measured config).
// Early exit: own-segment T >= global T, so breaking when all lanes have
// T < T_EXIT under-counts by at most T_EXIT per pixel; checked every 2 visits.
// ---------------------------------------------------------------------------
__global__ __launch_bounds__(512, 4) void render_kernel(
    const float* __restrict__ gp, float* __restrict__ out)
{
    __shared__ alignas(16) float sgrec[N_G * 8];   // 32 KB
    __shared__ float comb[7][4][128];              // 14 KB
    __shared__ int wc0[8], wc1[8];

    const int t    = threadIdx.x;
    const int lane = t & 63;
    const int w    = t >> 6;

    // block -> tile permutation: 512 tiles (16 x-tiles, 32 y-tiles).
    const int bi = blockIdx.x;
    const int i  = bi & 255;
    const int qq = bi >> 8;         // 0 or 1
    const int x0 = i & 15;
    const int y0 = i >> 4;          // 0..15
    const int tx = qq ? ((x0 + 8) & 15) : x0;
    const int ty = qq ? (y0 + 16) : y0;

    const float cx = (float)(tx << 4) + 7.5f;
    const float cy = (float)(ty << 3) + 3.5f;

    const float4* cullA = (const float4*)gp;
    const float4* cullB = (const float4*)(gp + 4096);
    const float*  rec   = gp + 8192;

    // exact ellipse-vs-rect test (rect = pixel centers of tile)
    auto keep_test = [&](int g) -> bool {
        const float4 A = cullA[g];   // mx,my,alpha,beta
        const float4 B = cullB[g];   // gamma,L,e1,e2
        const float bx0 = cx - 7.5f - A.x, bx1 = bx0 + 15.0f;
        const float by0 = cy - 3.5f - A.y, by1 = by0 + 7.0f;
        float dy = fminf(fmaxf(B.z * bx0, by0), by1);
        float qm = fmaf(B.x * dy, dy, bx0 * fmaf(A.w, dy, A.z * bx0));
        dy = fminf(fmaxf(B.z * bx1, by0), by1);
        qm = fminf(qm, fmaf(B.x * dy, dy, bx1 * fmaf(A.w, dy, A.z * bx1)));
        float dxq = fminf(fmaxf(B.w * by0, bx0), bx1);
        qm = fminf(qm, fmaf(A.z * dxq, dxq, by0 * fmaf(A.w, dxq, B.x * by0)));
        dxq = fminf(fmaxf(B.w * by1, bx0), bx1);
        qm = fminf(qm, fmaf(A.z * dxq, dxq, by1 * fmaf(A.w, dxq, B.x * by1)));
        if ((bx0 <= 0.0f) & (bx1 >= 0.0f) & (by0 <= 0.0f) & (by1 >= 0.0f))
            qm = 0.0f;
        return qm <= B.y;
    };

    // --- cull + order-preserving compaction + stage records to LDS ---
    const int ga = t, gb = 512 + t;
    const bool keepA = keep_test(ga);
    const bool keepB = keep_test(gb);
    const unsigned long long bmA = __ballot(keepA);
    const unsigned long long bmB = __ballot(keepB);
    if (lane == 0) { wc0[w] = __popcll(bmA); wc1[w] = __popcll(bmB); }
    __syncthreads();
    int baseA = 0, baseB = 0, sumA = 0, total = 0;
    #pragma unroll
    for (int ii = 0; ii < 8; ++ii) {
        const int c0 = wc0[ii], c1 = wc1[ii];
        if (ii < w) { baseA += c0; baseB += c1; }
        sumA  += c0;
        total += c0 + c1;
    }
    if (keepA) {
        const int pos = baseA + __popcll(bmA & ((1ull << lane) - 1ull));
        const float4* s4 = (const float4*)(rec + ga*8);
        float4* dst = (float4*)&sgrec[pos * 8];
        dst[0] = s4[0]; dst[1] = s4[1];
    }
    if (keepB) {
        const int pos = sumA + baseB + __popcll(bmB & ((1ull << lane) - 1ull));
        const float4* s4 = (const float4*)(rec + gb*8);
        float4* dst = (float4*)&sgrec[pos * 8];
        dst[0] = s4[0]; dst[1] = s4[1];
    }
    __syncthreads();

    // --- composite: 2 pixels per lane, segments over depth ---
    const int lx = lane & 15;
    const int ly = lane >> 4;       // 0..3
    const int s  = w;               // segment 0..7
    const int px  = (tx << 4) + lx;
    const int py0 = (ty << 3) + ly; // second pixel at py0+4
    const float fpx = (float)px, fpy0 = (float)py0;

    const int seg = (total + 7) >> 3;
    const int k0 = s * seg;
    const int k1 = (k0 + seg < total) ? (k0 + seg) : total;

    float T0 = 1.0f, cr0 = 0.0f, cg0 = 0.0f, cb0 = 0.0f;
    float T1 = 1.0f, cr1 = 0.0f, cg1 = 0.0f, cb1 = 0.0f;

    int iter = 0;
    for (int k = k0; k < k1; ++k) {
        const float4* g4 = (const float4*)&sgrec[k * 8];
        const float4 A = g4[0];  // mx,my,c2,c3
        const float4 B = g4[1];  // c4,c5,rg16,b

        const float dx   = fpx - A.x;           // shared between both pixels
        const float c2dx = A.z * dx;
        const float dy0  = fpy0 - A.y;
        const float dy1  = dy0 + 4.0f;

        const float t10 = fmaf(A.w, dy0, c2dx);
        const float t11 = fmaf(A.w, dy1, c2dx);
        const float h0  = fmaf(B.x * dy0, dy0, B.y);
        const float h1  = fmaf(B.x * dy1, dy1, B.y);
        const float P0  = fmaf(dx, t10, h0);
        const float P1  = fmaf(dx, t11, h1);
        const float al0 = __builtin_amdgcn_exp2f(P0);
        const float al1 = __builtin_amdgcn_exp2f(P1);

        unsigned rgbits = __float_as_uint(B.z);
        const float2 rg = __half22float2(*reinterpret_cast<__half2*>(&rgbits));

        const float w0 = T0 * al0;
        const float w1 = T1 * al1;
        cr0 = fmaf(w0, rg.x, cr0);  cr1 = fmaf(w1, rg.x, cr1);
        cg0 = fmaf(w0, rg.y, cg0);  cg1 = fmaf(w1, rg.y, cg1);
        cb0 = fmaf(w0, B.w, cb0);   cb1 = fmaf(w1, B.w, cb1);
        T0  = fmaf(-al0, T0, T0);   T1  = fmaf(-al1, T1, T1);

        // conservative early exit (own-T >= global-T), every 2 visits
        if (((++iter) & 1) == 0 && __all(fmaxf(T0, T1) < T_EXIT)) break;
    }

    if (s > 0) {
        comb[s-1][0][lane]    = T0;
        comb[s-1][1][lane]    = cr0;
        comb[s-1][2][lane]    = cg0;
        comb[s-1][3][lane]    = cb0;
        comb[s-1][0][lane+64] = T1;
        comb[s-1][1][lane+64] = cr1;
        comb[s-1][2][lane+64] = cg1;
        comb[s-1][3][lane+64] = cb1;
    }
    __syncthreads();

    if (s == 0) {
        #pragma unroll
        for (int si = 0; si < 7; ++si) {
            cr0 = fmaf(T0, comb[si][1][lane], cr0);
            cg0 = fmaf(T0, comb[si][2][lane], cg0);
            cb0 = fmaf(T0, comb[si][3][lane], cb0);
            T0 *= comb[si][0][lane];
            cr1 = fmaf(T1, comb[si][1][lane+64], cr1);
            cg1 = fmaf(T1, comb[si][2][lane+64], cg1);
            cb1 = fmaf(T1, comb[si][3][lane+64], cb1);
            T1 *= comb[si][0][lane+64];
        }
        const int pid0 = py0 * IMG_W + px;
        const int pid1 = (py0 + 4) * IMG_W + px;
        out[pid0*3 + 0] = cr0;
        out[pid0*3 + 1] = cg0;
        out[pid0*3 + 2] = cb0;
        out[pid1*3 + 0] = cr1;
        out[pid1*3 + 1] = cg1;
        out[pid1*3 + 2] = cb1;
    }
}

extern "C" void kernel_launch(void* const* d_in, const int* in_sizes, int n_in,
                              void* d_out, int out_size, void* d_ws, size_t ws_size,
                              hipStream_t stream) {
    const float* means3D   = (const float*)d_in[0];
    const float* covs3d    = (const float*)d_in[1];
    const float* colors    = (const float*)d_in[2];
    const float* opacities = (const float*)d_in[3];
    const float* Km        = (const float*)d_in[4];
    const float* Rm        = (const float*)d_in[5];
    const float* tv        = (const float*)d_in[6];

    float* gp = (float*)d_ws;   // 64 KB used

    hipLaunchKernelGGL(prep_sort_kernel, dim3(64), dim3(256), 0, stream,
                       means3D, covs3d, colors, opacities, Km, Rm, tv, gp);
    hipLaunchKernelGGL(render_kernel, dim3(512), dim3(512), 0, stream,
                       gp, (float*)d_out);
}